// Round 5
// baseline (27.388 us; speedup 1.0000x reference)
//
#include <hip/hip_runtime.h>
#include <hip/hip_bf16.h>

// out[b,d] = ortho[d,0]*(var[o,0]^2*ns[b,0]) + ortho[d,1]*(var[o,1]^2*ns[b,1]) + mu[o,d]
//   o = idx[b].  D=128, R=2, NOBJ=9.  img unused.
// HBM-write-bound: ~67 MB store + ~17 MB fetch -> ~12.4 us pure-traffic floor.
// R5: 1024 blocks x 128 rows, 16-deep static pipeline (longer steady state,
// fewer block ramps), nontemporal loads for the streamed idx/ns, NT stores.

#define VAE_D 128
#define GPB   16   // groups (of 8 rows) per block

typedef float f32x4 __attribute__((ext_vector_type(4)));
typedef float f32x2 __attribute__((ext_vector_type(2)));

__global__ __launch_bounds__(256)
void vae_embed_kernel(const int* __restrict__ idx,
                      const float* __restrict__ ns,      // [B, 128]
                      const float* __restrict__ ortho,   // [128, 128] row-major
                      const float* __restrict__ mu,      // [9, 128]
                      const float* __restrict__ var,     // [9, 2]
                      float* __restrict__ out,           // [B, 128]
                      int B)
{
    const int t    = threadIdx.x;
    const int lane = t & 31;            // 32 lanes cover one row (4 floats each)
    const int grp  = t >> 5;            // 8 row-slots per block
    const int d0   = lane << 2;

    // Loop-invariant ortho column pairs (L1-hot after first wave per CU).
    const float2 oc0 = *reinterpret_cast<const float2*>(ortho + (size_t)(d0 + 0) * VAE_D);
    const float2 oc1 = *reinterpret_cast<const float2*>(ortho + (size_t)(d0 + 1) * VAE_D);
    const float2 oc2 = *reinterpret_cast<const float2*>(ortho + (size_t)(d0 + 2) * VAE_D);
    const float2 oc3 = *reinterpret_cast<const float2*>(ortho + (size_t)(d0 + 3) * VAE_D);

    const int groups = B >> 3;                 // row-groups of 8
    const int g0 = blockIdx.x * GPB;

    if (g0 + GPB <= groups) {
        // ---- fast path: 16-deep static pipeline ----
        int   o[GPB];
        f32x2 n[GPB];

        #pragma unroll
        for (int u = 0; u < GPB; ++u) {        // phase 1: 16 independent idx loads
            const int b = ((g0 + u) << 3) + grp;
            o[u] = __builtin_nontemporal_load(idx + b);
        }
        #pragma unroll
        for (int u = 0; u < GPB; ++u) {        // phase 2: 16 independent ns loads
            const int b = ((g0 + u) << 3) + grp;
            n[u] = __builtin_nontemporal_load(
                       reinterpret_cast<const f32x2*>(ns + (size_t)b * VAE_D));
        }
        #pragma unroll
        for (int u = 0; u < GPB; ++u) {        // phase 3: dependent gather+compute+store
            const int b = ((g0 + u) << 3) + grp;
            const float2 v = *reinterpret_cast<const float2*>(var + o[u] * 2);
            const float a0 = v.x * v.x * n[u].x;
            const float a1 = v.y * v.y * n[u].y;
            const float4 m = *reinterpret_cast<const float4*>(mu + (size_t)o[u] * VAE_D + d0);
            f32x4 r;
            r.x = fmaf(oc0.x, a0, fmaf(oc0.y, a1, m.x));
            r.y = fmaf(oc1.x, a0, fmaf(oc1.y, a1, m.y));
            r.z = fmaf(oc2.x, a0, fmaf(oc2.y, a1, m.z));
            r.w = fmaf(oc3.x, a0, fmaf(oc3.y, a1, m.w));
            __builtin_nontemporal_store(r,
                reinterpret_cast<f32x4*>(out + (size_t)b * VAE_D + d0));
        }
    } else {
        // ---- generic tail (unused when B % (8*GPB) == 0) ----
        for (int g = g0; g < groups; ++g) {
            const int b = (g << 3) + grp;
            const int o = idx[b];
            const float2 n01 = *reinterpret_cast<const float2*>(ns + (size_t)b * VAE_D);
            const float2 v   = *reinterpret_cast<const float2*>(var + o * 2);
            const float a0 = v.x * v.x * n01.x;
            const float a1 = v.y * v.y * n01.y;
            const float4 m = *reinterpret_cast<const float4*>(mu + (size_t)o * VAE_D + d0);
            float4 r;
            r.x = fmaf(oc0.x, a0, fmaf(oc0.y, a1, m.x));
            r.y = fmaf(oc1.x, a0, fmaf(oc1.y, a1, m.y));
            r.z = fmaf(oc2.x, a0, fmaf(oc2.y, a1, m.z));
            r.w = fmaf(oc3.x, a0, fmaf(oc3.y, a1, m.w));
            *reinterpret_cast<float4*>(out + (size_t)b * VAE_D + d0) = r;
        }
    }
}

extern "C" void kernel_launch(void* const* d_in, const int* in_sizes, int n_in,
                              void* d_out, int out_size, void* d_ws, size_t ws_size,
                              hipStream_t stream)
{
    // inputs: img[B,4], random_int[B], normal_sample[B,128],
    //         orthogonal_set[128,128], mu_[9,128], var_[9,2]
    const int*   idx   = (const int*)  d_in[1];
    const float* ns    = (const float*)d_in[2];
    const float* ortho = (const float*)d_in[3];
    const float* mu    = (const float*)d_in[4];
    const float* var   = (const float*)d_in[5];
    float* out = (float*)d_out;

    const int B = in_sizes[1];
    const int groups = B >> 3;                         // 16384 for B=131072
    const int grid = (groups + GPB - 1) / GPB;         // 1024 blocks (128 rows each)

    vae_embed_kernel<<<grid, 256, 0, stream>>>(idx, ns, ortho, mu, var, out, B);
}

// Round 6
// 22.509 us; speedup vs baseline: 1.2168x; 1.2168x over previous
//
#include <hip/hip_runtime.h>
#include <hip/hip_bf16.h>

// out[b,d] = ortho[d,0]*(var[o,0]^2*ns[b,0]) + ortho[d,1]*(var[o,1]^2*ns[b,1]) + mu[o,d]
//   o = idx[b].  D=128, R=2, NOBJ=9.  img unused.
// HBM-write-bound: ~67 MB store + ~10-17 MB fetch -> ~11.5 us pure-traffic floor.
// R6: exact R4 structure (GPB=8, 2048 blocks = 8 blocks/CU = 32 waves/CU max
// occupancy, 8-deep static pipeline, regular loads) but REGULAR stores —
// isolating the NT-store variable. R5 showed occupancy halving costs 7 us,
// so 2048 blocks is pinned.

#define VAE_D 128
#define GPB   8    // groups (of 8 rows) per block -> 64 rows/block

__global__ __launch_bounds__(256)
void vae_embed_kernel(const int* __restrict__ idx,
                      const float* __restrict__ ns,      // [B, 128]
                      const float* __restrict__ ortho,   // [128, 128] row-major
                      const float* __restrict__ mu,      // [9, 128]
                      const float* __restrict__ var,     // [9, 2]
                      float* __restrict__ out,           // [B, 128]
                      int B)
{
    const int t    = threadIdx.x;
    const int lane = t & 31;            // 32 lanes cover one row (4 floats each)
    const int grp  = t >> 5;            // 8 row-slots per block
    const int d0   = lane << 2;

    // Loop-invariant ortho column pairs (L1-hot after first block per CU).
    const float2 oc0 = *reinterpret_cast<const float2*>(ortho + (size_t)(d0 + 0) * VAE_D);
    const float2 oc1 = *reinterpret_cast<const float2*>(ortho + (size_t)(d0 + 1) * VAE_D);
    const float2 oc2 = *reinterpret_cast<const float2*>(ortho + (size_t)(d0 + 2) * VAE_D);
    const float2 oc3 = *reinterpret_cast<const float2*>(ortho + (size_t)(d0 + 3) * VAE_D);

    const int groups = B >> 3;                 // row-groups of 8
    const int g0 = blockIdx.x * GPB;

    if (g0 + GPB <= groups) {
        // ---- fast path: 8-deep static pipeline ----
        int    o[GPB];
        float2 n[GPB];

        #pragma unroll
        for (int u = 0; u < GPB; ++u) {        // phase 1: independent idx loads
            const int b = ((g0 + u) << 3) + grp;
            o[u] = idx[b];
        }
        #pragma unroll
        for (int u = 0; u < GPB; ++u) {        // phase 2: independent ns loads
            const int b = ((g0 + u) << 3) + grp;
            n[u] = *reinterpret_cast<const float2*>(ns + (size_t)b * VAE_D);
        }
        #pragma unroll
        for (int u = 0; u < GPB; ++u) {        // phase 3: dependent gather+compute+store
            const int b = ((g0 + u) << 3) + grp;
            const float2 v = *reinterpret_cast<const float2*>(var + o[u] * 2);
            const float a0 = v.x * v.x * n[u].x;
            const float a1 = v.y * v.y * n[u].y;
            const float4 m = *reinterpret_cast<const float4*>(mu + (size_t)o[u] * VAE_D + d0);
            float4 r;
            r.x = fmaf(oc0.x, a0, fmaf(oc0.y, a1, m.x));
            r.y = fmaf(oc1.x, a0, fmaf(oc1.y, a1, m.y));
            r.z = fmaf(oc2.x, a0, fmaf(oc2.y, a1, m.z));
            r.w = fmaf(oc3.x, a0, fmaf(oc3.y, a1, m.w));
            *reinterpret_cast<float4*>(out + (size_t)b * VAE_D + d0) = r;
        }
    } else {
        // ---- generic tail (unused when B % (8*GPB) == 0) ----
        for (int g = g0; g < groups; ++g) {
            const int b = (g << 3) + grp;
            const int o = idx[b];
            const float2 n01 = *reinterpret_cast<const float2*>(ns + (size_t)b * VAE_D);
            const float2 v   = *reinterpret_cast<const float2*>(var + o * 2);
            const float a0 = v.x * v.x * n01.x;
            const float a1 = v.y * v.y * n01.y;
            const float4 m = *reinterpret_cast<const float4*>(mu + (size_t)o * VAE_D + d0);
            float4 r;
            r.x = fmaf(oc0.x, a0, fmaf(oc0.y, a1, m.x));
            r.y = fmaf(oc1.x, a0, fmaf(oc1.y, a1, m.y));
            r.z = fmaf(oc2.x, a0, fmaf(oc2.y, a1, m.z));
            r.w = fmaf(oc3.x, a0, fmaf(oc3.y, a1, m.w));
            *reinterpret_cast<float4*>(out + (size_t)b * VAE_D + d0) = r;
        }
    }
}

extern "C" void kernel_launch(void* const* d_in, const int* in_sizes, int n_in,
                              void* d_out, int out_size, void* d_ws, size_t ws_size,
                              hipStream_t stream)
{
    // inputs: img[B,4], random_int[B], normal_sample[B,128],
    //         orthogonal_set[128,128], mu_[9,128], var_[9,2]
    const int*   idx   = (const int*)  d_in[1];
    const float* ns    = (const float*)d_in[2];
    const float* ortho = (const float*)d_in[3];
    const float* mu    = (const float*)d_in[4];
    const float* var   = (const float*)d_in[5];
    float* out = (float*)d_out;

    const int B = in_sizes[1];
    const int groups = B >> 3;                         // 16384 for B=131072
    const int grid = (groups + GPB - 1) / GPB;         // 2048 blocks (64 rows each)

    vae_embed_kernel<<<grid, 256, 0, stream>>>(idx, ns, ortho, mu, var, out, B);
}

// Round 7
// 20.405 us; speedup vs baseline: 1.3422x; 1.1031x over previous
//
#include <hip/hip_runtime.h>
#include <hip/hip_bf16.h>

// out[b,d] = ortho[d,0]*(var[o,0]^2*ns[b,0]) + ortho[d,1]*(var[o,1]^2*ns[b,1]) + mu[o,d]
//   o = idx[b].  D=128, R=2, NOBJ=9.  img unused.
// HBM-write-bound: ~67 MB NT store + ~10 MB fetch -> ~11.5 us traffic floor.
// R7: exact R4 structure (GPB=8, 2048 blocks, 8-deep pipeline, regular loads,
// NT stores — R6 A/B showed NT store is -2.5 us) + __launch_bounds__(256,8)
// to pin VGPR <= 64 so all 8 blocks/CU (32 waves/CU) are co-resident.

#define VAE_D 128
#define GPB   8    // groups (of 8 rows) per block -> 64 rows/block

typedef float f32x4 __attribute__((ext_vector_type(4)));

__global__ __launch_bounds__(256, 8)   // 8 waves/EU -> 8 blocks/CU -> VGPR<=64
void vae_embed_kernel(const int* __restrict__ idx,
                      const float* __restrict__ ns,      // [B, 128]
                      const float* __restrict__ ortho,   // [128, 128] row-major
                      const float* __restrict__ mu,      // [9, 128]
                      const float* __restrict__ var,     // [9, 2]
                      float* __restrict__ out,           // [B, 128]
                      int B)
{
    const int t    = threadIdx.x;
    const int lane = t & 31;            // 32 lanes cover one row (4 floats each)
    const int grp  = t >> 5;            // 8 row-slots per block
    const int d0   = lane << 2;

    // Loop-invariant ortho column pairs (L1-hot after first block per CU).
    const float2 oc0 = *reinterpret_cast<const float2*>(ortho + (size_t)(d0 + 0) * VAE_D);
    const float2 oc1 = *reinterpret_cast<const float2*>(ortho + (size_t)(d0 + 1) * VAE_D);
    const float2 oc2 = *reinterpret_cast<const float2*>(ortho + (size_t)(d0 + 2) * VAE_D);
    const float2 oc3 = *reinterpret_cast<const float2*>(ortho + (size_t)(d0 + 3) * VAE_D);

    const int groups = B >> 3;                 // row-groups of 8
    const int g0 = blockIdx.x * GPB;

    if (g0 + GPB <= groups) {
        // ---- fast path: 8-deep static pipeline ----
        int    o[GPB];
        float2 n[GPB];

        #pragma unroll
        for (int u = 0; u < GPB; ++u) {        // phase 1: independent idx loads
            const int b = ((g0 + u) << 3) + grp;
            o[u] = idx[b];
        }
        #pragma unroll
        for (int u = 0; u < GPB; ++u) {        // phase 2: independent ns loads
            const int b = ((g0 + u) << 3) + grp;
            n[u] = *reinterpret_cast<const float2*>(ns + (size_t)b * VAE_D);
        }
        #pragma unroll
        for (int u = 0; u < GPB; ++u) {        // phase 3: dependent gather+compute+store
            const int b = ((g0 + u) << 3) + grp;
            const float2 v = *reinterpret_cast<const float2*>(var + o[u] * 2);
            const float a0 = v.x * v.x * n[u].x;
            const float a1 = v.y * v.y * n[u].y;
            const float4 m = *reinterpret_cast<const float4*>(mu + (size_t)o[u] * VAE_D + d0);
            f32x4 r;
            r.x = fmaf(oc0.x, a0, fmaf(oc0.y, a1, m.x));
            r.y = fmaf(oc1.x, a0, fmaf(oc1.y, a1, m.y));
            r.z = fmaf(oc2.x, a0, fmaf(oc2.y, a1, m.z));
            r.w = fmaf(oc3.x, a0, fmaf(oc3.y, a1, m.w));
            __builtin_nontemporal_store(r,
                reinterpret_cast<f32x4*>(out + (size_t)b * VAE_D + d0));
        }
    } else {
        // ---- generic tail (unused when B % (8*GPB) == 0) ----
        for (int g = g0; g < groups; ++g) {
            const int b = (g << 3) + grp;
            const int o = idx[b];
            const float2 n01 = *reinterpret_cast<const float2*>(ns + (size_t)b * VAE_D);
            const float2 v   = *reinterpret_cast<const float2*>(var + o * 2);
            const float a0 = v.x * v.x * n01.x;
            const float a1 = v.y * v.y * n01.y;
            const float4 m = *reinterpret_cast<const float4*>(mu + (size_t)o * VAE_D + d0);
            float4 r;
            r.x = fmaf(oc0.x, a0, fmaf(oc0.y, a1, m.x));
            r.y = fmaf(oc1.x, a0, fmaf(oc1.y, a1, m.y));
            r.z = fmaf(oc2.x, a0, fmaf(oc2.y, a1, m.z));
            r.w = fmaf(oc3.x, a0, fmaf(oc3.y, a1, m.w));
            *reinterpret_cast<float4*>(out + (size_t)b * VAE_D + d0) = r;
        }
    }
}

extern "C" void kernel_launch(void* const* d_in, const int* in_sizes, int n_in,
                              void* d_out, int out_size, void* d_ws, size_t ws_size,
                              hipStream_t stream)
{
    // inputs: img[B,4], random_int[B], normal_sample[B,128],
    //         orthogonal_set[128,128], mu_[9,128], var_[9,2]
    const int*   idx   = (const int*)  d_in[1];
    const float* ns    = (const float*)d_in[2];
    const float* ortho = (const float*)d_in[3];
    const float* mu    = (const float*)d_in[4];
    const float* var   = (const float*)d_in[5];
    float* out = (float*)d_out;

    const int B = in_sizes[1];
    const int groups = B >> 3;                         // 16384 for B=131072
    const int grid = (groups + GPB - 1) / GPB;         // 2048 blocks (64 rows each)

    vae_embed_kernel<<<grid, 256, 0, stream>>>(idx, ns, ortho, mu, var, out, B);
}